// Round 7
// baseline (288.919 us; speedup 1.0000x reference)
//
#include <hip/hip_runtime.h>
#include <hip/hip_bf16.h>

#define LRELU(val) ((val) >= 0.0f ? (val) : 0.01f * (val))

__device__ __forceinline__ float dot4(float4 a, float4 b, float acc) {
    return fmaf(a.x, b.x, fmaf(a.y, b.y, fmaf(a.z, b.z, fmaf(a.w, b.w, acc))));
}

__device__ __forceinline__ float wdot4(const float* __restrict__ wbase, int c, int q,
                                       float4 a, float acc) {
    acc = fmaf(a.x, wbase[(4 * q + 0) * 32 + c], acc);
    acc = fmaf(a.y, wbase[(4 * q + 1) * 32 + c], acc);
    acc = fmaf(a.z, wbase[(4 * q + 2) * 32 + c], acc);
    acc = fmaf(a.w, wbase[(4 * q + 3) * 32 + c], acc);
    return acc;
}

__device__ __forceinline__ float4 sub4(float4 a, float4 b) {
    return make_float4(a.x - b.x, a.y - b.y, a.z - b.z, a.w - b.w);
}

__device__ __forceinline__ unsigned long long key_of(float d2, int idx) {
    unsigned u = __float_as_uint(d2);
    u = (d2 < 0.0f) ? ~u : (u | 0x80000000u);
    return ((unsigned long long)u << 32) | (unsigned)idx;
}

__device__ inline int lower_bound_i(const int* __restrict__ a, int n, int v) {
    int lo = 0, hi = n;
    while (lo < hi) {
        int m = (lo + hi) >> 1;
        if (a[m] < v) lo = m + 1; else hi = m;
    }
    return lo;
}

// Rank counting, NS slots, keys read in chunks of 8 (8 independent ds_reads
// in flight; round-6 was 2-deep and stalled at VALUBusy 50%).
#define CNT8(RR, KK) RR += (int)(a0 < KK) + (int)(a1 < KK) + (int)(a2 < KK) + (int)(a3 < KK) \
                         + (int)(a4 < KK) + (int)(a5 < KK) + (int)(a6 < KK) + (int)(a7 < KK)
#define CNT1(RR, KK) RR += (int)(aa < KK)

template <int NS>
__device__ __forceinline__ void count_ranks(const unsigned long long* __restrict__ sK, int len,
    unsigned long long k0, unsigned long long k1, unsigned long long k2,
    unsigned long long k3, unsigned long long k4, unsigned long long k5,
    int& r0, int& r1, int& r2, int& r3, int& r4, int& r5)
{
    int tt = 0;
#pragma unroll 1
    for (; tt + 8 <= len; tt += 8) {
        unsigned long long a0 = sK[tt + 0], a1 = sK[tt + 1], a2 = sK[tt + 2], a3 = sK[tt + 3],
                           a4 = sK[tt + 4], a5 = sK[tt + 5], a6 = sK[tt + 6], a7 = sK[tt + 7];
        CNT8(r0, k0);
        if (NS > 1) CNT8(r1, k1);
        if (NS > 2) CNT8(r2, k2);
        if (NS > 3) CNT8(r3, k3);
        if (NS > 4) CNT8(r4, k4);
        if (NS > 5) CNT8(r5, k5);
    }
#pragma unroll 1
    for (; tt < len; ++tt) {
        unsigned long long aa = sK[tt];
        CNT1(r0, k0);
        if (NS > 1) CNT1(r1, k1);
        if (NS > 2) CNT1(r2, k2);
        if (NS > 3) CNT1(r3, k3);
        if (NS > 4) CNT1(r4, k4);
        if (NS > 5) CNT1(r5, k5);
    }
}

// ---------------------------------------------------------------------------
// Kernel 1: both MLP2 encoders + sq norms + group-offset tables.
// ---------------------------------------------------------------------------
__launch_bounds__(256)
__global__ void encode_kernel(const float* __restrict__ x_pfc, const float* __restrict__ x_vtx,
                              const int* __restrict__ bpfc, const int* __restrict__ bvtx,
                              const float* __restrict__ pw1, const float* __restrict__ pb1,
                              const float* __restrict__ pw2, const float* __restrict__ pb2,
                              const float* __restrict__ vw1, const float* __restrict__ vb1,
                              const float* __restrict__ vw2, const float* __restrict__ vb2,
                              float* __restrict__ pfc_enc, float* __restrict__ pfc_norm,
                              float* __restrict__ vtx_enc, float* __restrict__ vtx_norm,
                              int* __restrict__ goff_pfc, int* __restrict__ goff_vtx) {
    __shared__ float h1s[8][32];
    const int t = threadIdx.x;
    const int c = t & 31;
    const int nl = t >> 5;

    if (blockIdx.x == 0) {
        if (t < 33) goff_pfc[t] = lower_bound_i(bpfc, 8192, t);
        else if (t >= 64 && t < 97) goff_vtx[t - 64] = lower_bound_i(bvtx, 2048, t - 64);
    }

    const bool is_pfc = (blockIdx.x < 1024);
    const int node = (is_pfc ? blockIdx.x : (blockIdx.x - 1024)) * 8 + nl;
    const int din = is_pfc ? 7 : 4;
    const float* __restrict__ xin = is_pfc ? (x_pfc + node * 7) : (x_vtx + node * 4);
    const float* __restrict__ w1 = is_pfc ? pw1 : vw1;
    const float* __restrict__ b1 = is_pfc ? pb1 : vb1;
    const float* __restrict__ w2 = is_pfc ? pw2 : vw2;
    const float* __restrict__ b2 = is_pfc ? pb2 : vb2;
    float* __restrict__ enc  = is_pfc ? pfc_enc : vtx_enc;
    float* __restrict__ nrm  = is_pfc ? pfc_norm : vtx_norm;

    float h1 = b1[c];
    for (int d = 0; d < din; ++d) h1 = fmaf(xin[d], w1[d * 32 + c], h1);
    h1 = LRELU(h1);
    h1s[nl][c] = h1;
    __syncthreads();

    float h2 = b2[c];
#pragma unroll
    for (int d = 0; d < 32; ++d) h2 = fmaf(h1s[nl][d], w2[d * 32 + c], h2);
    h2 = LRELU(h2);
    enc[node * 32 + c] = h2;

    float s = h2 * h2;
#pragma unroll
    for (int m = 16; m >= 1; m >>= 1) s += __shfl_xor(s, m);
    if (c == 0) nrm[node] = s;
}

// ---------------------------------------------------------------------------
// One wave = one dst node's full edge conv: distance keys -> LDS, rank-count
// selection (slot count dispatched on wave-uniform len), stage 16 neighbor
// rows, conv + max-pool. Two __syncthreads inside (uniform across waves).
// sNbrW aliases the sKey region (cross-wave overlap — the barrier after the
// count phase fences it).
// ---------------------------------------------------------------------------
__device__ __forceinline__ float edge_conv_wave(
    float4 xi0, float4 xi1, float4 xi2, float4 xi3,
    float4 xi4, float4 xi5, float4 xi6, float4 xi7, float ni,
    const float* __restrict__ srcf, const float* __restrict__ srcn,
    int start, int len, int Ns,
    const float* __restrict__ sW, const float* __restrict__ sB,
    unsigned long long* __restrict__ sKeyW, float4* __restrict__ sNbrW,
    int* __restrict__ widxW, int lane)
{
    const unsigned long long KMAX = ~0ull;

    // Phase 1: distance keys.  d2 = (ni + nj) - 2*dot (ref formula); key is
    // unique (idx in low bits) so ranks are exact incl. top_k tie order.
#pragma unroll 1
    for (int s = lane; s < len; s += 64) {
        const float4* rr = reinterpret_cast<const float4*>(srcf + (size_t)(start + s) * 32);
        float dot = 0.0f;
        dot = dot4(rr[0], xi0, dot); dot = dot4(rr[1], xi1, dot);
        dot = dot4(rr[2], xi2, dot); dot = dot4(rr[3], xi3, dot);
        dot = dot4(rr[4], xi4, dot); dot = dot4(rr[5], xi5, dot);
        dot = dot4(rr[6], xi6, dot); dot = dot4(rr[7], xi7, dot);
        float d2 = (ni + srcn[start + s]) - 2.0f * dot;
        sKeyW[s] = key_of(d2, start + s);
    }
    __syncthreads();

    unsigned long long k0 = KMAX, k1 = KMAX, k2 = KMAX, k3 = KMAX, k4 = KMAX, k5 = KMAX;
    if (lane + 0 * 64 < len) k0 = sKeyW[lane + 0 * 64];
    if (lane + 1 * 64 < len) k1 = sKeyW[lane + 1 * 64];
    if (lane + 2 * 64 < len) k2 = sKeyW[lane + 2 * 64];
    if (lane + 3 * 64 < len) k3 = sKeyW[lane + 3 * 64];
    if (lane + 4 * 64 < len) k4 = sKeyW[lane + 4 * 64];
    if (lane + 5 * 64 < len) k5 = sKeyW[lane + 5 * 64];

    int r0 = 0, r1 = 0, r2 = 0, r3 = 0, r4 = 0, r5 = 0;
    const int nsl = (len + 63) >> 6;   // wave-uniform
    if (nsl <= 1)      count_ranks<1>(sKeyW, len, k0, k1, k2, k3, k4, k5, r0, r1, r2, r3, r4, r5);
    else if (nsl == 2) count_ranks<2>(sKeyW, len, k0, k1, k2, k3, k4, k5, r0, r1, r2, r3, r4, r5);
    else if (nsl == 3) count_ranks<3>(sKeyW, len, k0, k1, k2, k3, k4, k5, r0, r1, r2, r3, r4, r5);
    else if (nsl == 4) count_ranks<4>(sKeyW, len, k0, k1, k2, k3, k4, k5, r0, r1, r2, r3, r4, r5);
    else if (nsl == 5) count_ranks<5>(sKeyW, len, k0, k1, k2, k3, k4, k5, r0, r1, r2, r3, r4, r5);
    else               count_ranks<6>(sKeyW, len, k0, k1, k2, k3, k4, k5, r0, r1, r2, r3, r4, r5);

    // Scatter winners (keys unique -> ranks unique, exactly 0..len-1)
    if (lane < 16) widxW[lane] = start;  // fallback, len<16 never in practice
    if (r0 < 16 && lane + 0 * 64 < len) widxW[r0] = start + lane + 0 * 64;
    if (r1 < 16 && lane + 1 * 64 < len) widxW[r1] = start + lane + 1 * 64;
    if (r2 < 16 && lane + 2 * 64 < len) widxW[r2] = start + lane + 2 * 64;
    if (r3 < 16 && lane + 3 * 64 < len) widxW[r3] = start + lane + 3 * 64;
    if (r4 < 16 && lane + 4 * 64 < len) widxW[r4] = start + lane + 4 * 64;
    if (r5 < 16 && lane + 5 * 64 < len) widxW[r5] = start + lane + 5 * 64;
    __syncthreads();   // all waves done with sKey before sNbr (aliased) writes

    // Stage 16 neighbor rows: 128 float4, 2 independent loads/lane. Issue the
    // loads, overlap with base compute, then write LDS.
    const int n0 = lane >> 3, q0 = lane & 7;
    const int n1 = (lane + 64) >> 3, q1 = lane & 7;
    int j0 = widxW[n0]; j0 = ((unsigned)j0 < (unsigned)Ns) ? j0 : 0;
    int j1 = widxW[n1]; j1 = ((unsigned)j1 < (unsigned)Ns) ? j1 : 0;
    float4 v0 = reinterpret_cast<const float4*>(srcf + (size_t)j0 * 32)[q0];
    float4 v1 = reinterpret_cast<const float4*>(srcf + (size_t)j1 * 32)[q1];

    const int c = lane & 31;
    float base = sB[c];
    base = wdot4(sW, c, 0, xi0, base); base = wdot4(sW, c, 1, xi1, base);
    base = wdot4(sW, c, 2, xi2, base); base = wdot4(sW, c, 3, xi3, base);
    base = wdot4(sW, c, 4, xi4, base); base = wdot4(sW, c, 5, xi5, base);
    base = wdot4(sW, c, 6, xi6, base); base = wdot4(sW, c, 7, xi7, base);

    sNbrW[n0 * 8 + q0] = v0;
    sNbrW[n1 * 8 + q1] = v1;
    // same-wave DS ops are in-order: conv reads below see the writes

    const int half = lane >> 5;
    const float* sW2nd = sW + 1024;   // rows 32..63 (the x_j - x_i part)
    float vmax = -__builtin_huge_valf();
#pragma unroll 1
    for (int r = 0; r < 8; ++r) {
        const float4* nb = sNbrW + (2 * r + half) * 8;
        float acc = base;
        acc = wdot4(sW2nd, c, 0, sub4(nb[0], xi0), acc);
        acc = wdot4(sW2nd, c, 1, sub4(nb[1], xi1), acc);
        acc = wdot4(sW2nd, c, 2, sub4(nb[2], xi2), acc);
        acc = wdot4(sW2nd, c, 3, sub4(nb[3], xi3), acc);
        acc = wdot4(sW2nd, c, 4, sub4(nb[4], xi4), acc);
        acc = wdot4(sW2nd, c, 5, sub4(nb[5], xi5), acc);
        acc = wdot4(sW2nd, c, 6, sub4(nb[6], xi6), acc);
        acc = wdot4(sW2nd, c, 7, sub4(nb[7], xi7), acc);
        vmax = fmaxf(vmax, LRELU(acc));
    }
    vmax = fmaxf(vmax, __shfl_xor(vmax, 32));
    return vmax;   // lanes hold channel (lane&31)
}

// ---------------------------------------------------------------------------
// Kernel 2: FUSED conv1 + conv2. conv2's dst row for node i IS conv1's output
// for node i (node-local) -> keep it in LDS (f1row), share conv weights,
// never materialize feats1/n_f1 in global.
// ---------------------------------------------------------------------------
__launch_bounds__(256)
__global__ void fused_conv_kernel(
    const float* __restrict__ pfc_enc, const float* __restrict__ n_pfc,
    const float* __restrict__ vtx_enc, const float* __restrict__ n_vtx,
    const int* __restrict__ bpfc,
    const int* __restrict__ goff_pfc, const int* __restrict__ goff_vtx,
    const float* __restrict__ W, const float* __restrict__ B,
    float* __restrict__ feats2)
{
    __shared__ float sW[2048];
    __shared__ float sB[32];
    __shared__ __align__(16) unsigned long long sKey[4][384];  // aliased by nbr staging
    __shared__ int widx[4][16];
    __shared__ __align__(16) float f1row[4][32];

    const int t = threadIdx.x;
    const int lane = t & 63;
    const int w = t >> 6;
    const int i = blockIdx.x * 4 + w;    // grid covers 8192 exactly

    for (int k = t; k < 2048; k += 256) sW[k] = W[k];
    if (t < 32) sB[t] = B[t];
    __syncthreads();

    unsigned long long* sKeyW = &sKey[w][0];
    float4* sNbrW = reinterpret_cast<float4*>(&sKey[0][0]) + w * 128;
    int* widxW = &widx[w][0];

    const int g = bpfc[i];

    // ---- conv1: src = dst = pfc_enc (group ~256±16) ----
    const float4* xr = reinterpret_cast<const float4*>(pfc_enc + (size_t)i * 32);
    const float4 xi0 = xr[0], xi1 = xr[1], xi2 = xr[2], xi3 = xr[3],
                 xi4 = xr[4], xi5 = xr[5], xi6 = xr[6], xi7 = xr[7];
    const int s1 = goff_pfc[g];
    const int len1 = min(goff_pfc[g + 1] - s1, 384);
    float v1 = edge_conv_wave(xi0, xi1, xi2, xi3, xi4, xi5, xi6, xi7, n_pfc[i],
                              pfc_enc, n_pfc, s1, len1, 8192,
                              sW, sB, sKeyW, sNbrW, widxW, lane);

    if (lane < 32) f1row[w][lane] = v1;     // lane<32 carries channel lane
    float nf1 = v1 * v1;
#pragma unroll
    for (int m = 16; m >= 1; m >>= 1) nf1 += __shfl_xor(nf1, m);  // |feats1_i|^2
    __syncthreads();   // fence: union reuse + f1row visibility

    // ---- conv2: dst = feats1 row (in LDS), src = vtx_enc (group ~64±8) ----
    const float4* fr = reinterpret_cast<const float4*>(&f1row[w][0]);
    const float4 y0 = fr[0], y1 = fr[1], y2 = fr[2], y3 = fr[3],
                 y4 = fr[4], y5 = fr[5], y6 = fr[6], y7 = fr[7];
    const int s2 = goff_vtx[g];
    const int len2 = min(goff_vtx[g + 1] - s2, 384);
    float v2 = edge_conv_wave(y0, y1, y2, y3, y4, y5, y6, y7, nf1,
                              vtx_enc, n_vtx, s2, len2, 2048,
                              sW, sB, sKeyW, sNbrW, widxW, lane);

    if (lane < 32) feats2[(size_t)i * 32 + lane] = v2;
}

// ---------------------------------------------------------------------------
// Kernel 3: output MLP 32 -> 64 -> 32 -> 4 -> 1 (lrelu each) + batch copy.
// ---------------------------------------------------------------------------
__launch_bounds__(256)
__global__ void out_mlp_kernel(const float* __restrict__ f2, const int* __restrict__ bpfc,
                               const float* __restrict__ w1, const float* __restrict__ b1,
                               const float* __restrict__ w2, const float* __restrict__ b2,
                               const float* __restrict__ w3, const float* __restrict__ b3,
                               const float* __restrict__ w4, const float* __restrict__ b4,
                               float* __restrict__ dout, int N) {
    __shared__ float sW1[32 * 64], sW2[64 * 32], sW3[32 * 4];
    __shared__ float sB1[64], sB2[32], sB3[4], sW4[4], sB4[1];
    __shared__ float ex1[4][64];
    __shared__ float ex2[4][32];

    const int t = threadIdx.x;
    for (int k = t; k < 2048; k += 256) { sW1[k] = w1[k]; sW2[k] = w2[k]; }
    if (t < 128) sW3[t] = w3[t];
    if (t < 64)  sB1[t] = b1[t];
    if (t < 32)  sB2[t] = b2[t];
    if (t < 4)   { sB3[t] = b3[t]; sW4[t] = w4[t]; }
    if (t == 0)  sB4[0] = b4[0];
    __syncthreads();

    const int w = t >> 6;
    const int lane = t & 63;
    const int i = blockIdx.x * 4 + w;

    const float* fr = f2 + (size_t)i * 32;

    float h1 = sB1[lane];
#pragma unroll
    for (int d = 0; d < 32; ++d) h1 = fmaf(fr[d], sW1[d * 64 + lane], h1);
    h1 = LRELU(h1);
    ex1[w][lane] = h1;
    __syncthreads();

    const int c = lane & 31;
    float h2 = sB2[c];
#pragma unroll
    for (int d = 0; d < 64; ++d) h2 = fmaf(ex1[w][d], sW2[d * 32 + c], h2);
    h2 = LRELU(h2);
    if (lane < 32) ex2[w][c] = h2;
    __syncthreads();

    float a0 = sB3[0], a1 = sB3[1], a2 = sB3[2], a3 = sB3[3];
#pragma unroll
    for (int d = 0; d < 32; ++d) {
        float e = ex2[w][d];
        a0 = fmaf(e, sW3[d * 4 + 0], a0);
        a1 = fmaf(e, sW3[d * 4 + 1], a1);
        a2 = fmaf(e, sW3[d * 4 + 2], a2);
        a3 = fmaf(e, sW3[d * 4 + 3], a3);
    }
    a0 = LRELU(a0); a1 = LRELU(a1); a2 = LRELU(a2); a3 = LRELU(a3);
    float o = sB4[0];
    o = fmaf(a0, sW4[0], o); o = fmaf(a1, sW4[1], o);
    o = fmaf(a2, sW4[2], o); o = fmaf(a3, sW4[3], o);
    o = LRELU(o);

    if (lane == 0) dout[i] = o;                       // output 0: (8192,1)
    if (lane == 1) dout[N + i] = (float)bpfc[i];      // output 1: batch_pfc
}

// ---------------------------------------------------------------------------
extern "C" void kernel_launch(void* const* d_in, const int* in_sizes, int n_in,
                              void* d_out, int out_size, void* d_ws, size_t ws_size,
                              hipStream_t stream) {
    const float* x_pfc     = (const float*)d_in[0];
    const float* x_vtx     = (const float*)d_in[1];
    const int*   batch_pfc = (const int*)d_in[2];
    const int*   batch_vtx = (const int*)d_in[3];
    const float* pfc_w1 = (const float*)d_in[4];
    const float* pfc_b1 = (const float*)d_in[5];
    const float* pfc_w2 = (const float*)d_in[6];
    const float* pfc_b2 = (const float*)d_in[7];
    const float* vtx_w1 = (const float*)d_in[8];
    const float* vtx_b1 = (const float*)d_in[9];
    const float* vtx_w2 = (const float*)d_in[10];
    const float* vtx_b2 = (const float*)d_in[11];
    const float* conv_w = (const float*)d_in[12];
    const float* conv_b = (const float*)d_in[13];
    const float* out_w1 = (const float*)d_in[14];
    const float* out_b1 = (const float*)d_in[15];
    const float* out_w2 = (const float*)d_in[16];
    const float* out_b2 = (const float*)d_in[17];
    const float* out_w3 = (const float*)d_in[18];
    const float* out_b3 = (const float*)d_in[19];
    const float* out_w4 = (const float*)d_in[20];
    const float* out_b4 = (const float*)d_in[21];

    const int N_PFC = 8192;

    float* ws = (float*)d_ws;
    float* pfc_enc = ws;                 // 8192*32
    float* vtx_enc = ws + 262144;        // 2048*32
    float* feats2  = ws + 327680;        // 8192*32
    float* n_pfc   = ws + 589824;        // 8192
    float* n_vtx   = ws + 598016;        // 2048
    int*   goff_pfc = (int*)(ws + 600064);   // 33
    int*   goff_vtx = (int*)(ws + 600128);   // 33

    encode_kernel<<<1280, 256, 0, stream>>>(x_pfc, x_vtx, batch_pfc, batch_vtx,
                                            pfc_w1, pfc_b1, pfc_w2, pfc_b2,
                                            vtx_w1, vtx_b1, vtx_w2, vtx_b2,
                                            pfc_enc, n_pfc, vtx_enc, n_vtx,
                                            goff_pfc, goff_vtx);

    fused_conv_kernel<<<2048, 256, 0, stream>>>(pfc_enc, n_pfc, vtx_enc, n_vtx,
                                                batch_pfc, goff_pfc, goff_vtx,
                                                conv_w, conv_b, feats2);

    out_mlp_kernel<<<2048, 256, 0, stream>>>(feats2, batch_pfc,
                                             out_w1, out_b1, out_w2, out_b2,
                                             out_w3, out_b3, out_w4, out_b4,
                                             (float*)d_out, N_PFC);
}